// Round 1
// baseline (507.472 us; speedup 1.0000x reference)
//
#include <hip/hip_runtime.h>

// ---------------- init: zero deg + pooling partials ----------------
__global__ void k_init(int* deg, unsigned int* partials_u32, int N) {
    int i = blockIdx.x * blockDim.x + threadIdx.x;
    if (i < N) deg[i] = 0;
    if (i < 512) partials_u32[i] = 0u;   // 256 doubles
}

// ---------------- in-degree (dst side only, matches reference) ----------------
__global__ void k_deg(const int* __restrict__ dst, int E, int* __restrict__ deg) {
    int e = blockIdx.x * blockDim.x + threadIdx.x;
    if (e < E) atomicAdd(&deg[dst[e]], 1);
}

// ---------------- prefix scan (chunk=256) part A: block sums ----------------
__global__ void k_scanA(const int* __restrict__ deg, int N, int* __restrict__ blockSums) {
    __shared__ int s[256];
    int t = threadIdx.x, i = blockIdx.x * 256 + t;
    s[t] = (i < N) ? deg[i] : 0;
    __syncthreads();
    for (int o = 128; o > 0; o >>= 1) {
        if (t < o) s[t] += s[t + o];
        __syncthreads();
    }
    if (t == 0) blockSums[blockIdx.x] = s[0];
}

// ---------------- part B: exclusive scan of block sums (single block) ----------------
__global__ void k_scan2(int* blockSums, int nb) {
    __shared__ int s[256];
    int t = threadIdx.x;
    s[t] = (t < nb) ? blockSums[t] : 0;
    __syncthreads();
    for (int o = 1; o < 256; o <<= 1) {
        int v = (t >= o) ? s[t - o] : 0;
        __syncthreads();
        s[t] += v;
        __syncthreads();
    }
    blockSums[t] = (t == 0) ? 0 : s[t - 1];
}

// ---------------- part C: rowptr / cursor / dinv ----------------
__global__ void k_scanC(const int* __restrict__ deg, int N, const int* __restrict__ blockOffs,
                        int* __restrict__ rowptr, int* __restrict__ cursor,
                        float* __restrict__ dinv) {
    __shared__ int s[256];
    int t = threadIdx.x, i = blockIdx.x * 256 + t;
    int d = (i < N) ? deg[i] : 0;
    s[t] = d;
    __syncthreads();
    for (int o = 1; o < 256; o <<= 1) {
        int v = (t >= o) ? s[t - o] : 0;
        __syncthreads();
        s[t] += v;
        __syncthreads();
    }
    if (i < N) {
        int p = blockOffs[blockIdx.x] + s[t] - d;   // exclusive prefix
        rowptr[i] = p;
        cursor[i] = p;
        dinv[i] = 1.0f / sqrtf((float)(d + 1));     // +1 self loop
        if (i == N - 1) rowptr[N] = p + d;
    }
}

// ---------------- CSR fill: bucket src by dst ----------------
__global__ void k_fill(const int* __restrict__ src, const int* __restrict__ dst, int E,
                       int* __restrict__ cursor, int* __restrict__ col) {
    int e = blockIdx.x * blockDim.x + threadIdx.x;
    if (e < E) {
        int pos = atomicAdd(&cursor[dst[e]], 1);
        col[pos] = src[e];
    }
}

// ---------------- linear K=10: g = dinv * (x @ W1) ----------------
__global__ void k_lin10(const float* __restrict__ x, const float* __restrict__ W,
                        const float* __restrict__ dinv, float* __restrict__ g, int N) {
    int tid = blockIdx.x * blockDim.x + threadIdx.x;
    int node = tid >> 6, f = tid & 63;
    if (node >= N) return;
    float acc = 0.f;
    #pragma unroll
    for (int k = 0; k < 10; ++k) acc += x[node * 10 + k] * W[k * 64 + f];
    g[node * 64 + f] = dinv[node] * acc;
}

// ---------------- linear K=64 (W staged in LDS): g = dinv * (in @ W) ----------------
__global__ void k_lin64(const float* __restrict__ in, const float* __restrict__ W,
                        const float* __restrict__ dinv, float* __restrict__ g, int N) {
    __shared__ float sW[64 * 64];
    int t = threadIdx.x;
    for (int i = t; i < 64 * 64; i += blockDim.x) sW[i] = W[i];
    __syncthreads();
    int tid = blockIdx.x * blockDim.x + t;
    int node = tid >> 6, f = tid & 63;
    if (node >= N) return;
    const float* row = in + (size_t)node * 64;
    float acc = 0.f;
    #pragma unroll 8
    for (int k = 0; k < 64; ++k) acc += row[k] * sW[k * 64 + f];
    g[(size_t)node * 64 + f] = dinv[node] * acc;
}

// ---------------- aggregate + bias + relu (layers 1,2). wave=node, lane=feature ----------------
__global__ void k_gather_relu(const float* __restrict__ g, const int* __restrict__ rowptr,
                              const int* __restrict__ col, const float* __restrict__ dinv,
                              const float* __restrict__ b, float* __restrict__ out, int N) {
    int tid = blockIdx.x * blockDim.x + threadIdx.x;
    int node = tid >> 6, f = tid & 63;
    if (node >= N) return;
    float acc = g[(size_t)node * 64 + f];           // self loop (already dinv-scaled)
    int s0 = rowptr[node], s1 = rowptr[node + 1];
    for (int e = s0; e < s1; ++e) {
        int j = col[e];                              // wave-uniform
        acc += g[(size_t)j * 64 + f];
    }
    float v = dinv[node] * acc + b[f];
    out[(size_t)node * 64 + f] = fmaxf(v, 0.f);
}

// ---------------- layer-3 aggregate fused with mean-pool dot fcW ----------------
__global__ void k_gather_pool(const float* __restrict__ g, const int* __restrict__ rowptr,
                              const int* __restrict__ col, const float* __restrict__ dinv,
                              const float* __restrict__ b, const float* __restrict__ fcW,
                              double* __restrict__ partials, int N) {
    int tid = blockIdx.x * blockDim.x + threadIdx.x;
    int node = tid >> 6, f = tid & 63;
    float prod = 0.f;
    if (node < N) {
        float acc = g[(size_t)node * 64 + f];
        int s0 = rowptr[node], s1 = rowptr[node + 1];
        for (int e = s0; e < s1; ++e) acc += g[(size_t)col[e] * 64 + f];
        float v = dinv[node] * acc + b[f];
        prod = v * fcW[f];
    }
    // wave-wide (64) reduction
    for (int o = 32; o > 0; o >>= 1) prod += __shfl_down(prod, o, 64);
    if ((threadIdx.x & 63) == 0 && node < N)
        atomicAdd(&partials[blockIdx.x & 255], (double)prod);
}

// ---------------- final: sum partials, divide by N, add fcb ----------------
__global__ void k_final(const double* __restrict__ partials, const float* __restrict__ fcb,
                        float* __restrict__ out, double invN) {
    __shared__ double s[256];
    int t = threadIdx.x;
    s[t] = partials[t];
    __syncthreads();
    for (int o = 128; o > 0; o >>= 1) {
        if (t < o) s[t] += s[t + o];
        __syncthreads();
    }
    if (t == 0) out[0] = (float)(s[0] * invN) + fcb[0];
}

extern "C" void kernel_launch(void* const* d_in, const int* in_sizes, int n_in,
                              void* d_out, int out_size, void* d_ws, size_t ws_size,
                              hipStream_t stream) {
    const float* x   = (const float*)d_in[0];
    const int*   ei  = (const int*)d_in[1];
    const float* W1  = (const float*)d_in[2];
    const float* b1  = (const float*)d_in[3];
    const float* W2  = (const float*)d_in[4];
    const float* b2  = (const float*)d_in[5];
    const float* W3  = (const float*)d_in[6];
    const float* b3  = (const float*)d_in[7];
    const float* fcW = (const float*)d_in[8];
    const float* fcb = (const float*)d_in[9];

    const int N = in_sizes[0] / 10;
    const int E = in_sizes[1] / 2;
    const int* src = ei;
    const int* dst = ei + E;

    // ---- workspace carve-up (256B aligned) ----
    char* w = (char*)d_ws;
    size_t off = 0;
    auto alloc = [&](size_t bytes) -> void* {
        void* p = w + off;
        off += (bytes + 255) & ~(size_t)255;
        return p;
    };
    int*    deg       = (int*)alloc((size_t)N * 4);
    float*  dinv      = (float*)alloc((size_t)N * 4);
    int*    rowptr    = (int*)alloc((size_t)(N + 1) * 4);
    int*    cursor    = (int*)alloc((size_t)N * 4);
    int*    col       = (int*)alloc((size_t)E * 4);
    int*    blockSums = (int*)alloc(256 * 4);
    double* partials  = (double*)alloc(256 * 8);
    float*  bufA      = (float*)alloc((size_t)N * 64 * 4);
    float*  bufB      = (float*)alloc((size_t)N * 64 * 4);
    (void)ws_size; (void)n_in; (void)out_size;

    const int nbScan     = (N + 255) / 256;       // 196 for N=50000
    const int nbEdges    = (E + 255) / 256;
    const int nodeBlocks = (N + 3) / 4;           // 4 node-waves per 256-block
    const int nbInit     = ((N > 512 ? N : 512) + 255) / 256;

    // ---- graph preprocessing (every call: ws is re-poisoned) ----
    k_init <<<nbInit, 256, 0, stream>>>(deg, (unsigned int*)partials, N);
    k_deg  <<<nbEdges, 256, 0, stream>>>(dst, E, deg);
    k_scanA<<<nbScan, 256, 0, stream>>>(deg, N, blockSums);
    k_scan2<<<1, 256, 0, stream>>>(blockSums, nbScan);
    k_scanC<<<nbScan, 256, 0, stream>>>(deg, N, blockSums, rowptr, cursor, dinv);
    k_fill <<<nbEdges, 256, 0, stream>>>(src, dst, E, cursor, col);

    // ---- layer 1: F_in=10 -> 64, relu ----
    k_lin10<<<nodeBlocks, 256, 0, stream>>>(x, W1, dinv, bufA, N);
    k_gather_relu<<<nodeBlocks, 256, 0, stream>>>(bufA, rowptr, col, dinv, b1, bufB, N);
    // ---- layer 2: 64 -> 64, relu ----
    k_lin64<<<nodeBlocks, 256, 0, stream>>>(bufB, W2, dinv, bufA, N);
    k_gather_relu<<<nodeBlocks, 256, 0, stream>>>(bufA, rowptr, col, dinv, b2, bufB, N);
    // ---- layer 3: 64 -> 64, fused mean-pool + fc ----
    k_lin64<<<nodeBlocks, 256, 0, stream>>>(bufB, W3, dinv, bufA, N);
    k_gather_pool<<<nodeBlocks, 256, 0, stream>>>(bufA, rowptr, col, dinv, b3, fcW,
                                                  partials, N);
    k_final<<<1, 256, 0, stream>>>(partials, fcb, (float*)d_out, 1.0 / (double)N);
}

// Round 2
// 321.497 us; speedup vs baseline: 1.5785x; 1.5785x over previous
//
#include <hip/hip_runtime.h>

// ---------------- init: zero deg + pooling partials ----------------
__global__ void k_init(int* deg, unsigned int* pool_u32, int N) {
    int i = blockIdx.x * blockDim.x + threadIdx.x;
    if (i < N) deg[i] = 0;
    if (i < 32 * 64 * 2) pool_u32[i] = 0u;   // 32x64 doubles
}

// ---------------- in-degree (dst side only, matches reference) ----------------
__global__ void k_deg(const int* __restrict__ dst, int E, int* __restrict__ deg) {
    int e = blockIdx.x * blockDim.x + threadIdx.x;
    if (e < E) atomicAdd(&deg[dst[e]], 1);
}

// ---------------- prefix scan part A: block sums ----------------
__global__ void k_scanA(const int* __restrict__ deg, int N, int* __restrict__ blockSums) {
    __shared__ int s[256];
    int t = threadIdx.x, i = blockIdx.x * 256 + t;
    s[t] = (i < N) ? deg[i] : 0;
    __syncthreads();
    for (int o = 128; o > 0; o >>= 1) {
        if (t < o) s[t] += s[t + o];
        __syncthreads();
    }
    if (t == 0) blockSums[blockIdx.x] = s[0];
}

// ---------------- part B: exclusive scan of block sums (single block) ----------------
__global__ void k_scan2(int* blockSums, int nb) {
    __shared__ int s[256];
    int t = threadIdx.x;
    s[t] = (t < nb) ? blockSums[t] : 0;
    __syncthreads();
    for (int o = 1; o < 256; o <<= 1) {
        int v = (t >= o) ? s[t - o] : 0;
        __syncthreads();
        s[t] += v;
        __syncthreads();
    }
    blockSums[t] = (t == 0) ? 0 : s[t - 1];
}

// ---------------- part C: rowptr / cursor / dinv ----------------
__global__ void k_scanC(const int* __restrict__ deg, int N, const int* __restrict__ blockOffs,
                        int* __restrict__ rowptr, int* __restrict__ cursor,
                        float* __restrict__ dinv) {
    __shared__ int s[256];
    int t = threadIdx.x, i = blockIdx.x * 256 + t;
    int d = (i < N) ? deg[i] : 0;
    s[t] = d;
    __syncthreads();
    for (int o = 1; o < 256; o <<= 1) {
        int v = (t >= o) ? s[t - o] : 0;
        __syncthreads();
        s[t] += v;
        __syncthreads();
    }
    if (i < N) {
        int p = blockOffs[blockIdx.x] + s[t] - d;   // exclusive prefix
        rowptr[i] = p;
        cursor[i] = p;
        dinv[i] = 1.0f / sqrtf((float)(d + 1));     // +1 self loop
        if (i == N - 1) rowptr[N] = p + d;
    }
}

// ---------------- CSR fill: bucket src by dst ----------------
__global__ void k_fill(const int* __restrict__ src, const int* __restrict__ dst, int E,
                       int* __restrict__ cursor, int* __restrict__ col) {
    int e = blockIdx.x * blockDim.x + threadIdx.x;
    if (e < E) {
        int pos = atomicAdd(&cursor[dst[e]], 1);
        col[pos] = src[e];
    }
}

// ---------------- layer 1 fused: gather raw x (10-wide) -> h1 -> g1 = dinv*h1 ----------------
// wave = node; lanes 0..9 carry the 10 input features during the gather.
__global__ void k_layer1(const float* __restrict__ x, const float* __restrict__ W1,
                         const float* __restrict__ b1, const int* __restrict__ rowptr,
                         const int* __restrict__ col, const float* __restrict__ dinv,
                         float* __restrict__ g1, int N) {
    __shared__ float sW[10 * 64];
    __shared__ float sB[64];
    int t = threadIdx.x;
    for (int i = t; i < 10 * 64; i += 256) sW[i] = W1[i];
    if (t < 64) sB[t] = b1[t];
    __syncthreads();
    int wid = (blockIdx.x * 256 + t) >> 6;
    int lane = t & 63;
    if (wid >= N) return;
    const bool act = lane < 10;
    float di = dinv[wid];
    float ax = act ? di * x[wid * 10 + lane] : 0.f;   // self loop term (dinv_i * x_i)
    int s0 = rowptr[wid], s1 = rowptr[wid + 1];
    int e = s0;
    for (; e + 4 <= s1; e += 4) {
        int j0 = col[e], j1 = col[e + 1], j2 = col[e + 2], j3 = col[e + 3];
        float d0 = dinv[j0], d1 = dinv[j1], d2 = dinv[j2], d3 = dinv[j3];
        float v0 = 0.f, v1 = 0.f, v2 = 0.f, v3 = 0.f;
        if (act) {
            v0 = x[j0 * 10 + lane]; v1 = x[j1 * 10 + lane];
            v2 = x[j2 * 10 + lane]; v3 = x[j3 * 10 + lane];
        }
        ax += d0 * v0 + d1 * v1 + d2 * v2 + d3 * v3;
    }
    for (; e < s1; ++e) {
        int j = col[e];
        float dj = dinv[j];
        float v = act ? x[j * 10 + lane] : 0.f;
        ax += dj * v;
    }
    float a1 = di * ax;                  // P_i(x)[lane] for lane<10
    float acc = sB[lane];
    #pragma unroll
    for (int k = 0; k < 10; ++k)
        acc += __shfl(a1, k, 64) * sW[k * 64 + lane];
    float h = fmaxf(acc, 0.f);
    g1[(size_t)wid * 64 + lane] = di * h;
}

// ---------------- layer 2 fused: gather g1 -> a2 -> h2 = relu(a2@W2+b2) -> g2 = dinv*h2 ----------------
__global__ void k_layer2(const float* __restrict__ g1, const float* __restrict__ W2,
                         const float* __restrict__ b2, const int* __restrict__ rowptr,
                         const int* __restrict__ col, const float* __restrict__ dinv,
                         float* __restrict__ g2, int N) {
    __shared__ float sW[64 * 64];
    __shared__ float sB[64];
    int t = threadIdx.x;
    for (int i = t; i < 64 * 64; i += 256) sW[i] = W2[i];
    if (t < 64) sB[t] = b2[t];
    __syncthreads();
    int wid = (blockIdx.x * 256 + t) >> 6;
    int lane = t & 63;
    if (wid >= N) return;
    float di = dinv[wid];
    size_t base = (size_t)wid * 64;
    float acc = g1[base + lane];         // self loop (already dinv_j-scaled)
    int s0 = rowptr[wid], s1 = rowptr[wid + 1];
    int e = s0;
    for (; e + 4 <= s1; e += 4) {
        int j0 = col[e], j1 = col[e + 1], j2 = col[e + 2], j3 = col[e + 3];
        float v0 = g1[(size_t)j0 * 64 + lane];
        float v1 = g1[(size_t)j1 * 64 + lane];
        float v2 = g1[(size_t)j2 * 64 + lane];
        float v3 = g1[(size_t)j3 * 64 + lane];
        acc += (v0 + v1) + (v2 + v3);
    }
    for (; e < s1; ++e) acc += g1[(size_t)col[e] * 64 + lane];
    float a2 = di * acc;                 // P_i(h1)[lane]
    float s = sB[lane];
    #pragma unroll
    for (int k = 0; k < 64; ++k)
        s += __shfl(a2, k, 64) * sW[k * 64 + lane];
    float h = fmaxf(s, 0.f);
    g2[base + lane] = di * h;
}

// ---------------- layer 3 + pool: gather g2 -> a3 = P_i(h2); pool += a3 ----------------
__global__ void k_layer3pool(const float* __restrict__ g2, const int* __restrict__ rowptr,
                             const int* __restrict__ col, const float* __restrict__ dinv,
                             double* __restrict__ pool, int N) {
    __shared__ float sred[256];
    int t = threadIdx.x;
    int wid = (blockIdx.x * 256 + t) >> 6;
    int lane = t & 63;
    float a3 = 0.f;
    if (wid < N) {
        float di = dinv[wid];
        size_t base = (size_t)wid * 64;
        float acc = g2[base + lane];     // self loop
        int s0 = rowptr[wid], s1 = rowptr[wid + 1];
        int e = s0;
        for (; e + 4 <= s1; e += 4) {
            int j0 = col[e], j1 = col[e + 1], j2 = col[e + 2], j3 = col[e + 3];
            float v0 = g2[(size_t)j0 * 64 + lane];
            float v1 = g2[(size_t)j1 * 64 + lane];
            float v2 = g2[(size_t)j2 * 64 + lane];
            float v3 = g2[(size_t)j3 * 64 + lane];
            acc += (v0 + v1) + (v2 + v3);
        }
        for (; e < s1; ++e) acc += g2[(size_t)col[e] * 64 + lane];
        a3 = di * acc;
    }
    sred[t] = a3;
    __syncthreads();
    if (t < 128) sred[t] += sred[t + 128];
    __syncthreads();
    if (t < 64) {
        float v = sred[t] + sred[t + 64];
        atomicAdd(&pool[(blockIdx.x & 31) * 64 + t], (double)v);
    }
}

// ---------------- final: p = mean(a3); out = p@(W3@fcW) + b3@fcW + fcb ----------------
__global__ void k_final(const double* __restrict__ pool, const float* __restrict__ W3,
                        const float* __restrict__ fcW, const float* __restrict__ b3,
                        const float* __restrict__ fcb, float* __restrict__ out, double invN) {
    int f = threadIdx.x;   // 64 threads, one wave
    double p = 0.0;
    for (int s = 0; s < 32; ++s) p += pool[s * 64 + f];
    float pm = (float)(p * invN);        // mean(P(h2))[f]
    float w = 0.f;                        // (W3@fcW)[f]
    #pragma unroll 8
    for (int j = 0; j < 64; ++j) w += W3[f * 64 + j] * fcW[j];
    float contrib = pm * w + b3[f] * fcW[f];
    for (int o = 32; o > 0; o >>= 1) contrib += __shfl_down(contrib, o, 64);
    if (f == 0) out[0] = contrib + fcb[0];
}

extern "C" void kernel_launch(void* const* d_in, const int* in_sizes, int n_in,
                              void* d_out, int out_size, void* d_ws, size_t ws_size,
                              hipStream_t stream) {
    const float* x   = (const float*)d_in[0];
    const int*   ei  = (const int*)d_in[1];
    const float* W1  = (const float*)d_in[2];
    const float* b1  = (const float*)d_in[3];
    const float* W2  = (const float*)d_in[4];
    const float* b2  = (const float*)d_in[5];
    const float* W3  = (const float*)d_in[6];
    const float* b3  = (const float*)d_in[7];
    const float* fcW = (const float*)d_in[8];
    const float* fcb = (const float*)d_in[9];

    const int N = in_sizes[0] / 10;
    const int E = in_sizes[1] / 2;
    const int* src = ei;
    const int* dst = ei + E;

    // ---- workspace carve-up (256B aligned) ----
    char* w = (char*)d_ws;
    size_t off = 0;
    auto alloc = [&](size_t bytes) -> void* {
        void* p = w + off;
        off += (bytes + 255) & ~(size_t)255;
        return p;
    };
    int*    deg       = (int*)alloc((size_t)N * 4);
    float*  dinv      = (float*)alloc((size_t)N * 4);
    int*    rowptr    = (int*)alloc((size_t)(N + 1) * 4);
    int*    cursor    = (int*)alloc((size_t)N * 4);
    int*    col       = (int*)alloc((size_t)E * 4);
    int*    blockSums = (int*)alloc(256 * 4);
    double* pool      = (double*)alloc(32 * 64 * 8);
    float*  g1        = (float*)alloc((size_t)N * 64 * 4);
    float*  g2        = (float*)alloc((size_t)N * 64 * 4);
    (void)ws_size; (void)n_in; (void)out_size;

    const int nbScan     = (N + 255) / 256;
    const int nbEdges    = (E + 255) / 256;
    const int nodeBlocks = (N + 3) / 4;           // 4 node-waves per 256-block
    const int nbInit     = ((N > 4096 ? N : 4096) + 255) / 256;

    // ---- graph preprocessing ----
    k_init <<<nbInit, 256, 0, stream>>>(deg, (unsigned int*)pool, N);
    k_deg  <<<nbEdges, 256, 0, stream>>>(dst, E, deg);
    k_scanA<<<nbScan, 256, 0, stream>>>(deg, N, blockSums);
    k_scan2<<<1, 256, 0, stream>>>(blockSums, nbScan);
    k_scanC<<<nbScan, 256, 0, stream>>>(deg, N, blockSums, rowptr, cursor, dinv);
    k_fill <<<nbEdges, 256, 0, stream>>>(src, dst, E, cursor, col);

    // ---- fused layers ----
    k_layer1<<<nodeBlocks, 256, 0, stream>>>(x, W1, b1, rowptr, col, dinv, g1, N);
    k_layer2<<<nodeBlocks, 256, 0, stream>>>(g1, W2, b2, rowptr, col, dinv, g2, N);
    k_layer3pool<<<nodeBlocks, 256, 0, stream>>>(g2, rowptr, col, dinv, pool, N);
    k_final<<<1, 64, 0, stream>>>(pool, W3, fcW, b3, fcb, (float*)d_out, 1.0 / (double)N);
}